// Round 1
// baseline (233794.751 us; speedup 1.0000x reference)
//
#include <hip/hip_runtime.h>
#include <math.h>

#define TENC 400
#define TMEL 800
#define NMEL 80
#define ENCD 768
#define PRE  256
#define ARNN 1024
#define DRNN 1024
#define ATTD 128

__device__ __forceinline__ float4 ld4(const float* p){ return *(const float4*)p; }
__device__ __forceinline__ float dot4(float4 a, float4 b){
  return a.x*b.x + a.y*b.y + a.z*b.z + a.w*b.w;
}
__device__ __forceinline__ float wred(float v){
  #pragma unroll
  for (int o = 32; o > 0; o >>= 1) v += __shfl_down(v, o);
  return v;
}
__device__ __forceinline__ float sigmf(float x){ return 1.f/(1.f + __expf(-x)); }

// ---------------- prenet: xs[t][b][256] ----------------
__global__ __launch_bounds__(256) void prenet_kernel(
    const float* __restrict__ din, const float* __restrict__ w1,
    const float* __restrict__ w2, float* __restrict__ xs)
{
  int t = blockIdx.x;
  __shared__ float f_s[32*80];
  __shared__ float p_s[32*256];
  for (int id = threadIdx.x; id < 32*80; id += 256) {
    int b = id / 80, m = id - b*80;
    f_s[id] = (t == 0) ? 0.f : din[b*(NMEL*TMEL) + m*TMEL + (t-1)];
  }
  __syncthreads();
  for (int b = 0; b < 32; ++b) {
    int k = threadIdx.x;
    float acc = 0.f;
    #pragma unroll 4
    for (int m = 0; m < 80; ++m) acc += f_s[b*80+m] * w1[k*80+m];
    p_s[b*256+k] = fmaxf(acc, 0.f);
  }
  __syncthreads();
  for (int b = 0; b < 32; ++b) {
    int j = threadIdx.x;
    float acc = 0.f;
    #pragma unroll 4
    for (int kk = 0; kk < 256; ++kk) acc += p_s[b*256+kk] * w2[j*256+kk];
    xs[t*(32*256) + b*256 + j] = fmaxf(acc, 0.f);
  }
}

// ---------------- pmem[b][t][128] = memory @ mem_w^T ----------------
__global__ __launch_bounds__(256) void pmem_kernel(
  const float* __restrict__ mem, const float* __restrict__ mw, float* __restrict__ pmem)
{
  int b = blockIdx.y, tc = blockIdx.x;           // 25 chunks of 16 t'
  int a = threadIdx.x & 127, th = threadIdx.x >> 7;
  for (int i = 0; i < 8; ++i) {
    int tt = tc*16 + th + 2*i;
    const float* mrow = mem + (size_t)b*(TENC*ENCD) + (size_t)tt*ENCD;
    const float* wrow = mw + a*ENCD;
    float acc = 0.f;
    #pragma unroll 4
    for (int e4 = 0; e4 < ENCD; e4 += 4) acc += dot4(ld4(mrow+e4), ld4(wrow+e4));
    pmem[b*(TENC*ATTD) + tt*ATTD + a] = acc;
  }
}

// ---------------- projection (device helper) ----------------
__device__ __forceinline__ void proj_task(int d, const float* dh, const float* ctx,
    const float* proj_w, const float* proj_b, const float* gate_w, const float* gate_b,
    float* out_mel, float* out_gate, int t)
{
  if (d >= 32*81) return;
  int b = d / 81, r = d - b*81;
  const float* w   = (r < 80) ? (proj_w + r*1792) : gate_w;
  const float* dhr = dh + b*DRNN;
  const float* cxr = ctx + b*ENCD;
  float acc = 0.f;
  #pragma unroll 4
  for (int k = 0; k < 1024; k += 4) acc += dot4(ld4(dhr+k), ld4(w+k));
  #pragma unroll 4
  for (int k = 0; k < 768;  k += 4) acc += dot4(ld4(cxr+k), ld4(w+1024+k));
  if (r < 80) out_mel[(b*80 + r)*TMEL + t] = acc + proj_b[r];
  else        out_gate[b*TMEL + t]         = acc + gate_b[0];
}

// ---------------- attention LSTM (+ folded projection of step t-1) ----------------
__global__ __launch_bounds__(256) void att_lstm_kernel(
  const float* __restrict__ xs_t, const float* __restrict__ ctx,
  const float* __restrict__ ah_in, float* __restrict__ ah_out, float* __restrict__ ac,
  const float* __restrict__ wih, const float* __restrict__ whh,
  const float* __restrict__ bih, const float* __restrict__ bhh,
  const float* __restrict__ dh_prev, const float* __restrict__ proj_w,
  const float* __restrict__ proj_b, const float* __restrict__ gate_w,
  const float* __restrict__ gate_b, float* __restrict__ out_mel,
  float* __restrict__ out_gate, int t)
{
  if (blockIdx.x >= 2048) {          // projection for step t-1
    if (t == 0) return;
    int d = (blockIdx.x - 2048)*256 + threadIdx.x;
    proj_task(d, dh_prev, ctx, proj_w, proj_b, gate_w, gate_b, out_mel, out_gate, t-1);
    return;
  }
  int b = blockIdx.x & 31, uc = blockIdx.x >> 5;
  int u0 = uc * 16;
  int q = threadIdx.x >> 6, lane = threadIdx.x & 63;
  __shared__ float G[4][16];
  const float* xrow = xs_t + b*PRE;
  const float* crow = ctx  + b*ENCD;
  const float* hrow = ah_in + b*ARNN;
  for (int du = 0; du < 16; ++du) {
    int j = q*1024 + u0 + du;
    const float* wi = wih + (size_t)j*1024;
    const float* wh = whh + (size_t)j*1024;
    int kl = lane*4;
    float acc = 0.f;
    #pragma unroll
    for (int i = 0; i < 8; ++i) {
      int k = i*256 + kl;
      float4 xv, wv;
      if (i == 0)      { xv = ld4(xrow + k);          wv = ld4(wi + k); }
      else if (i < 4)  { xv = ld4(crow + (k - 256));  wv = ld4(wi + k); }
      else             { xv = ld4(hrow + (k - 1024)); wv = ld4(wh + (k - 1024)); }
      acc += dot4(xv, wv);
    }
    acc = wred(acc);
    if (lane == 0) G[q][du] = acc + bih[j] + bhh[j];
  }
  __syncthreads();
  if (threadIdx.x < 16) {
    int u = u0 + threadIdx.x;
    float gi = G[0][threadIdx.x], gf = G[1][threadIdx.x];
    float gg = G[2][threadIdx.x], go = G[3][threadIdx.x];
    float c  = ac[b*ARNN + u];
    float cn = sigmf(gf)*c + sigmf(gi)*tanhf(gg);
    ac[b*ARNN + u]     = cn;
    ah_out[b*ARNN + u] = sigmf(go)*tanhf(cn);
  }
}

// ---------------- decoder LSTM ----------------
__global__ __launch_bounds__(256) void dec_lstm_kernel(
  const float* __restrict__ ah, const float* __restrict__ ctx,
  const float* __restrict__ dh_in, float* __restrict__ dh_out, float* __restrict__ dc,
  const float* __restrict__ wih, const float* __restrict__ whh,
  const float* __restrict__ bih, const float* __restrict__ bhh)
{
  int b = blockIdx.x & 31, uc = blockIdx.x >> 5;
  int u0 = uc * 16;
  int q = threadIdx.x >> 6, lane = threadIdx.x & 63;
  __shared__ float G[4][16];
  const float* arow = ah    + b*ARNN;
  const float* crow = ctx   + b*ENCD;
  const float* hrow = dh_in + b*DRNN;
  for (int du = 0; du < 16; ++du) {
    int j = q*1024 + u0 + du;
    const float* wi = wih + (size_t)j*1792;
    const float* wh = whh + (size_t)j*1024;
    int kl = lane*4;
    float acc = 0.f;
    #pragma unroll
    for (int i = 0; i < 11; ++i) {
      int k = i*256 + kl;
      float4 xv, wv;
      if (i < 4)       { xv = ld4(arow + k);          wv = ld4(wi + k); }
      else if (i < 7)  { xv = ld4(crow + (k - 1024)); wv = ld4(wi + k); }
      else             { xv = ld4(hrow + (k - 1792)); wv = ld4(wh + (k - 1792)); }
      acc += dot4(xv, wv);
    }
    acc = wred(acc);
    if (lane == 0) G[q][du] = acc + bih[j] + bhh[j];
  }
  __syncthreads();
  if (threadIdx.x < 16) {
    int u = u0 + threadIdx.x;
    float gi = G[0][threadIdx.x], gf = G[1][threadIdx.x];
    float gg = G[2][threadIdx.x], go = G[3][threadIdx.x];
    float c  = dc[b*DRNN + u];
    float cn = sigmf(gf)*c + sigmf(gi)*tanhf(gg);
    dc[b*DRNN + u]     = cn;
    dh_out[b*DRNN + u] = sigmf(go)*tanhf(cn);
  }
}

// ---------------- attention energies e[b][t'] ----------------
__global__ __launch_bounds__(256) void att_energy_kernel(
  const float* __restrict__ ah, const float* __restrict__ q_w,
  const float* __restrict__ pmem, const float* __restrict__ aw,
  const float* __restrict__ awc, const float* __restrict__ cw,
  const float* __restrict__ ldw, const float* __restrict__ vw,
  const int* __restrict__ mlen, float* __restrict__ e_out)
{
  int b = blockIdx.x >> 3, c8 = blockIdx.x & 7;
  int t0 = c8 * 50;
  __shared__ float pq_s[128], part2[256];
  __shared__ float aw_s[80], awc_s[80];
  __shared__ float loc_s[50][33];
  __shared__ float epart[50][4];
  int tid = threadIdx.x;
  if (tid < 160) {                       // halo: t0-15 .. t0+64
    int h = tid & 127; bool isC = tid >= 80;
    if (isC) h = tid - 80;
    int g = t0 - 15 + h;
    float v = (g >= 0 && g < TENC) ? (isC ? awc[b*TENC+g] : aw[b*TENC+g]) : 0.f;
    if (isC) awc_s[h] = v; else aw_s[h] = v;
  }
  { // pq = ah @ q_w^T, split K in halves
    int a = tid & 127, half = tid >> 7;
    const float* hr = ah  + b*ARNN + half*512;
    const float* qr = q_w + a*ARNN + half*512;
    float acc = 0.f;
    #pragma unroll 4
    for (int k = 0; k < 512; k += 4) acc += dot4(ld4(hr+k), ld4(qr+k));
    part2[tid] = acc;
  }
  __syncthreads();
  if (tid < 128) pq_s[tid] = part2[tid] + part2[tid+128];
  // location conv: loc[t'][f]
  for (int id = tid; id < 50*32; id += 256) {
    int tl = id >> 5, f = id & 31;
    const float* w0 = cw + f*62;
    const float* w1 = w0 + 31;
    float acc = 0.f;
    #pragma unroll
    for (int k = 0; k < 31; ++k)
      acc += aw_s[tl+k]*w0[k] + awc_s[tl+k]*w1[k];
    loc_s[tl][f] = acc;
  }
  __syncthreads();
  if (tid < 200) {
    int tl = tid >> 2, qa = tid & 3;
    int tt = t0 + tl;
    const float* pm = pmem + b*(TENC*ATTD) + tt*ATTD;
    float s = 0.f;
    for (int a = qa*32; a < qa*32 + 32; ++a) {
      const float* lw = ldw + a*32;
      float pl = 0.f;
      #pragma unroll 8
      for (int f = 0; f < 32; ++f) pl += loc_s[tl][f] * lw[f];
      s += vw[a] * tanhf(pq_s[a] + pm[a] + pl);
    }
    epart[tl][qa] = s;
  }
  __syncthreads();
  if (tid < 50) {
    int tt = t0 + tid;
    float v = epart[tid][0]+epart[tid][1]+epart[tid][2]+epart[tid][3];
    if (tt >= mlen[b]) v = -1000000000.0f;
    e_out[b*TENC + tt] = v;
  }
}

// ---------------- softmax + awc + alignments ----------------
__global__ __launch_bounds__(512) void softmax_kernel(
  const float* __restrict__ e, float* __restrict__ aw, float* __restrict__ awc,
  float* __restrict__ out_align, int t)
{
  int b = blockIdx.x, tid = threadIdx.x;
  __shared__ float red[512];
  float v = (tid < TENC) ? e[b*TENC+tid] : -3e38f;
  red[tid] = v; __syncthreads();
  for (int s = 256; s > 0; s >>= 1) {
    if (tid < s) red[tid] = fmaxf(red[tid], red[tid+s]);
    __syncthreads();
  }
  float mx = red[0]; __syncthreads();
  float ex = (tid < TENC) ? __expf(v - mx) : 0.f;
  red[tid] = ex; __syncthreads();
  for (int s = 256; s > 0; s >>= 1) {
    if (tid < s) red[tid] += red[tid+s];
    __syncthreads();
  }
  float inv = 1.f / red[0];
  if (tid < TENC) {
    float a = ex * inv;
    aw[b*TENC+tid] = a;
    awc[b*TENC+tid] += a;
    out_align[((size_t)b*TMEL + t)*TENC + tid] = a;
  }
}

// ---------------- ctx[b] = aw . memory[b] ----------------
__global__ __launch_bounds__(128) void ctx_kernel(
  const float* __restrict__ aw, const float* __restrict__ mem, float* __restrict__ ctx)
{
  int ch = blockIdx.x, b = blockIdx.y;
  __shared__ float aw_s[TENC];
  for (int id = threadIdx.x; id < TENC; id += 128) aw_s[id] = aw[b*TENC+id];
  __syncthreads();
  int j = ch*128 + threadIdx.x;
  const float* mrow = mem + (size_t)b*(TENC*ENCD) + j;
  float acc = 0.f;
  #pragma unroll 4
  for (int tt = 0; tt < TENC; ++tt) acc += aw_s[tt] * mrow[(size_t)tt*ENCD];
  ctx[b*ENCD + j] = acc;
}

// ---------------- standalone projection (final step) ----------------
__global__ __launch_bounds__(256) void proj_kernel(
  const float* __restrict__ dh, const float* __restrict__ ctx,
  const float* __restrict__ proj_w, const float* __restrict__ proj_b,
  const float* __restrict__ gate_w, const float* __restrict__ gate_b,
  float* __restrict__ out_mel, float* __restrict__ out_gate, int t)
{
  int d = blockIdx.x*256 + threadIdx.x;
  proj_task(d, dh, ctx, proj_w, proj_b, gate_w, gate_b, out_mel, out_gate, t);
}

extern "C" void kernel_launch(void* const* d_in, const int* in_sizes, int n_in,
                              void* d_out, int out_size, void* d_ws, size_t ws_size,
                              hipStream_t stream)
{
  const float* memory = (const float*)d_in[0];
  const float* din    = (const float*)d_in[1];
  const float* w1     = (const float*)d_in[3];
  const float* w2     = (const float*)d_in[4];
  const float* awih   = (const float*)d_in[5];
  const float* awhh   = (const float*)d_in[6];
  const float* abih   = (const float*)d_in[7];
  const float* abhh   = (const float*)d_in[8];
  const float* q_w    = (const float*)d_in[9];
  const float* mem_w  = (const float*)d_in[10];
  const float* v_w    = (const float*)d_in[11];
  const float* cw     = (const float*)d_in[12];
  const float* ldw    = (const float*)d_in[13];
  const float* dwih   = (const float*)d_in[14];
  const float* dwhh   = (const float*)d_in[15];
  const float* dbih   = (const float*)d_in[16];
  const float* dbhh   = (const float*)d_in[17];
  const float* pw     = (const float*)d_in[18];
  const float* pb     = (const float*)d_in[19];
  const float* gw     = (const float*)d_in[20];
  const float* gb     = (const float*)d_in[21];
  const int*   mlen   = (const int*)d_in[22];

  float* xs   = (float*)d_ws;                    // 800*32*256
  float* pmem = xs + 800*32*256;                 // 32*400*128
  float* st   = pmem + 32*400*128;
  float* ah0  = st;
  float* ah1  = ah0 + 32*1024;
  float* ac   = ah1 + 32*1024;
  float* dh0  = ac  + 32*1024;
  float* dh1  = dh0 + 32*1024;
  float* dc   = dh1 + 32*1024;
  float* ctx  = dc  + 32*1024;
  float* aw   = ctx + 32*768;
  float* awc  = aw  + 32*400;
  float* e    = awc + 32*400;

  float* out_mel   = (float*)d_out;              // (32,80,800)
  float* out_gate  = out_mel + 32*80*800;        // (32,800)
  float* out_align = out_gate + 32*800;          // (32,800,400)

  hipMemsetAsync(st, 0, (size_t)(6*32*1024 + 32*768 + 2*32*400)*sizeof(float), stream);
  prenet_kernel<<<TMEL, 256, 0, stream>>>(din, w1, w2, xs);
  pmem_kernel<<<dim3(25,32), 256, 0, stream>>>(memory, mem_w, pmem);

  for (int t = 0; t < TMEL; ++t) {
    float* ah_in  = (t & 1) ? ah1 : ah0;
    float* ah_out = (t & 1) ? ah0 : ah1;
    float* dh_in  = (t & 1) ? dh1 : dh0;
    float* dh_out = (t & 1) ? dh0 : dh1;
    att_lstm_kernel<<<2064, 256, 0, stream>>>(xs + t*32*256, ctx, ah_in, ah_out, ac,
        awih, awhh, abih, abhh, dh_in, pw, pb, gw, gb, out_mel, out_gate, t);
    att_energy_kernel<<<256, 256, 0, stream>>>(ah_out, q_w, pmem, aw, awc, cw, ldw,
        v_w, mlen, e);
    softmax_kernel<<<32, 512, 0, stream>>>(e, aw, awc, out_align, t);
    ctx_kernel<<<dim3(6,32), 128, 0, stream>>>(aw, memory, ctx);
    dec_lstm_kernel<<<2048, 256, 0, stream>>>(ah_out, ctx, dh_in, dh_out, dc,
        dwih, dwhh, dbih, dbhh);
  }
  proj_kernel<<<16, 256, 0, stream>>>(dh0, ctx, pw, pb, gw, gb, out_mel, out_gate, TMEL-1);
}